// Round 6
// baseline (1614.159 us; speedup 1.0000x reference)
//
#include <hip/hip_runtime.h>
#include <hip/hip_bf16.h>
#include <stdint.h>

// Problem constants
#define NHEAD 8
#define DMODEL 512
#define DVOCAB 32000
#define M_DIM 4096            // B*P
#define K_DIM 4096            // NHEAD*DMODEL
#define N_DIM 32000           // DVOCAB
#define NKT   128             // K_DIM / 32 k-tiles

typedef short bf16x8 __attribute__((ext_vector_type(8)));
typedef float f32x4 __attribute__((ext_vector_type(4)));
typedef unsigned short ushort8 __attribute__((ext_vector_type(8)));

template <int V> struct IC { static constexpr int v = V; };

__device__ __forceinline__ unsigned short f2bf(float f) {
    unsigned int u = __builtin_bit_cast(unsigned int, f);
    u = (u + 0x7fffu + ((u >> 16) & 1u)) >> 16;   // RNE (inputs are finite)
    return (unsigned short)u;
}

__device__ __forceinline__ void load16_to_lds(const void* g, void* l) {
    __builtin_amdgcn_global_load_lds(
        (const __attribute__((address_space(1))) unsigned int*)g,
        (__attribute__((address_space(3))) unsigned int*)l, 16, 0, 0);
}

// ---- x [4096][4096] f32 -> bf16, 8 elems/thread ----
__global__ void cvt_x(const float* __restrict__ in, unsigned short* __restrict__ out) {
    long t = (long)blockIdx.x * 256 + threadIdx.x;
    const float4* s = (const float4*)in + t * 2;
    float4 a = s[0], b = s[1];
    ushort8 o;
    o[0] = f2bf(a.x); o[1] = f2bf(a.y); o[2] = f2bf(a.z); o[3] = f2bf(a.w);
    o[4] = f2bf(b.x); o[5] = f2bf(b.y); o[6] = f2bf(b.z); o[7] = f2bf(b.w);
    *(ushort8*)(out + t * 8) = o;
}

// ---- W [H][V][D] f32 -> Wb [V][H*D] bf16 (B^T layout), 8 elems/thread ----
__global__ void cvt_w(const float* __restrict__ in, unsigned short* __restrict__ out) {
    int t = blockIdx.x * 256 + threadIdx.x;
    int d8 = t & 63;
    int hv = t >> 6;
    int h = hv / DVOCAB;
    int v = hv - h * DVOCAB;
    const float4* s = (const float4*)(in + (long)hv * DMODEL + d8 * 8);
    float4 a = s[0], b = s[1];
    ushort8 o;
    o[0] = f2bf(a.x); o[1] = f2bf(a.y); o[2] = f2bf(a.z); o[3] = f2bf(a.w);
    o[4] = f2bf(b.x); o[5] = f2bf(b.y); o[6] = f2bf(b.z); o[7] = f2bf(b.w);
    *(ushort8*)(out + (long)v * K_DIM + h * DMODEL + d8 * 8) = o;
}

// ---- bias [H][V] -> bsum [V] ----
__global__ void bias_red(const float* __restrict__ b, float* __restrict__ out) {
    int v = blockIdx.x * 256 + threadIdx.x;
    if (v >= DVOCAB) return;
    float s = 0.f;
    #pragma unroll
    for (int h = 0; h < NHEAD; ++h) s += b[h * DVOCAB + v];
    out[v] = s;
}

#define BAR()    __builtin_amdgcn_s_barrier()
#define LGKM0()  asm volatile("s_waitcnt lgkmcnt(0)" ::: "memory")
#define VMCNT8() asm volatile("s_waitcnt vmcnt(8)" ::: "memory")
#define VMCNT4() asm volatile("s_waitcnt vmcnt(4)" ::: "memory")
#define VMCNT0() asm volatile("s_waitcnt vmcnt(0)" ::: "memory")

// ---- bf16 GEMM, 128x128 tile, BK=32, 4-buffer ring, 2 blocks/CU ----
// C[M,N] = A[M,K] * Bt[N,K]^T + bias
// 256 threads = 4 waves (2x2), per-wave 64x64 output, 16 MFMA/tile/wave.
// LDS: 4 bufs x 16KB (A 128x32 | B 128x32). 64B rows -> ds_read_b128 frag
// reads are bank-uniform with NO swizzle (16 rows x 64B = all 32 banks).
// Ring ledger: during tile t, buf[(t+3)&3] holds tile t-1 (reads completed
// before t-1's LGKM0 -> trailing BAR) -> staging t+3 there is licensed.
// vmcnt(8) at tile t's first BAR drains tile t+1's 4 loads (issued at t-2,
// ~2 tile-times of lead > HBM latency). Never drains to 0 in steady state.
__global__ __launch_bounds__(256, 2) void gemm128(
    const unsigned short* __restrict__ A,   // [4096][4096] bf16
    const unsigned short* __restrict__ B,   // [32000][4096] bf16
    const float* __restrict__ bias,         // [32000]
    float* __restrict__ C)                  // [4096][32000] f32
{
    __shared__ __attribute__((aligned(16))) unsigned short lds[4][8192];

    const int tid = threadIdx.x;
    const int bid = blockIdx.x;
    // XCD-bijective swizzle: 8000 blocks, 8 XCDs, 1000 per XCD
    const int wg = (bid & 7) * 1000 + (bid >> 3);
    const int mt = wg & 31;            // 32 M-tiles (fast -> B-panel reuse)
    const int nt = wg >> 5;            // 250 N-tiles
    const long m0 = (long)mt * 128;
    const long n0 = (long)nt * 128;

    const int wid = tid >> 6, lane = tid & 63;
    const int wr = wid >> 1, wc = wid & 1;     // 2 x 2 waves
    const int lr = lane & 15, lk = lane >> 4;

    // frag read bases: rows of 32 elems (64B); chunk = lk, no swizzle needed
    const unsigned short* pA = &lds[0][0] + (wr * 64 + lr) * 32 + lk * 8;
    const unsigned short* pB = &lds[0][0] + 4096 + (wc * 64 + lr) * 32 + lk * 8;
    #define LDA(mi, BUF) (*(const bf16x8*)(pA + (mi) * 512 + (BUF) * 8192))
    #define LDB(nj, BUF) (*(const bf16x8*)(pB + (nj) * 512 + (BUF) * 8192))

    // staging: 16KB/tile = 4 x 16B per thread; per-lane byte offsets += 64/tile
    const char* Ab = (const char*)(A + m0 * K_DIM);
    const char* Bb = (const char*)(B + n0 * K_DIM);
    unsigned int a0 = (unsigned)((tid >> 2) * (K_DIM * 2) + (tid & 3) * 16);
    unsigned int a1 = a0 + 64u * (K_DIM * 2);
    unsigned int b0 = a0, b1 = a1;

    #define ST(BUF) do {                                   \
        char* _l = (char*)&lds[(BUF)][0] + tid * 16;       \
        load16_to_lds(Ab + a0, _l);                        \
        load16_to_lds(Ab + a1, _l + 4096);                 \
        load16_to_lds(Bb + b0, _l + 8192);                 \
        load16_to_lds(Bb + b1, _l + 12288);                \
        a0 += 64; a1 += 64; b0 += 64; b1 += 64; } while (0)

    f32x4 acc[4][4];
    #pragma unroll
    for (int i = 0; i < 4; ++i)
        #pragma unroll
        for (int j = 0; j < 4; ++j)
            acc[i][j] = (f32x4){0.f, 0.f, 0.f, 0.f};

    // prologue: stage tiles 0,1,2 (12 loads); drain tile0; sync
    ST(0); ST(1); ST(2);
    VMCNT8();
    BAR();

    auto body = [&](auto bufc, int t) {
        constexpr int BUF = decltype(bufc)::v;
        bf16x8 af[4], bf[4];
        #pragma unroll
        for (int mi = 0; mi < 4; ++mi) af[mi] = LDA(mi, BUF);
        #pragma unroll
        for (int nj = 0; nj < 4; ++nj) bf[nj] = LDB(nj, BUF);
        if (t + 3 < NKT) ST((BUF + 3) & 3);
        if (t < NKT - 3)       { VMCNT8(); }
        else if (t == NKT - 3) { VMCNT4(); }
        else                   { VMCNT0(); }
        BAR();
        LGKM0();
        __builtin_amdgcn_s_setprio(1);
        #pragma unroll
        for (int mi = 0; mi < 4; ++mi)
            #pragma unroll
            for (int nj = 0; nj < 4; ++nj)
                acc[mi][nj] = __builtin_amdgcn_mfma_f32_16x16x32_bf16(
                    af[mi], bf[nj], acc[mi][nj], 0, 0, 0);
        __builtin_amdgcn_s_setprio(0);
        BAR();
    };

    for (int t = 0; t < NKT; t += 4) {
        body(IC<0>{}, t);
        body(IC<1>{}, t + 1);
        body(IC<2>{}, t + 2);
        body(IC<3>{}, t + 3);
    }
    #undef LDA
    #undef LDB
    #undef ST

    // epilogue: C/D layout col = lane&15 (lr), row = lk*4 + reg; nontemporal
    #pragma unroll
    for (int nj = 0; nj < 4; ++nj) {
        const long col = n0 + wc * 64 + nj * 16 + lr;
        const float bs = bias[col];
        #pragma unroll
        for (int mi = 0; mi < 4; ++mi) {
            const long row = m0 + wr * 64 + mi * 16 + lk * 4;
            #pragma unroll
            for (int r = 0; r < 4; ++r)
                __builtin_nontemporal_store(acc[mi][nj][r] + bs,
                                            &C[(row + r) * (long)N_DIM + col]);
        }
    }
}

// ---- emergency fallback if ws too small: naive fp32 (slow but correct) ----
__global__ void naive_out(const float* __restrict__ x, const float* __restrict__ w,
                          const float* __restrict__ b, float* __restrict__ out) {
    long idx = (long)blockIdx.x * 256 + threadIdx.x;
    if (idx >= (long)M_DIM * N_DIM) return;
    long m = idx / N_DIM;
    int v = (int)(idx - m * N_DIM);
    float s = 0.f;
    for (int h = 0; h < NHEAD; ++h) {
        const float* xr = x + m * K_DIM + h * DMODEL;
        const float* wr = w + ((long)h * DVOCAB + v) * DMODEL;
        float ps = 0.f;
        for (int d = 0; d < DMODEL; ++d) ps += xr[d] * wr[d];
        s += ps + b[h * DVOCAB + v];
    }
    out[idx] = s;
}

extern "C" void kernel_launch(void* const* d_in, const int* in_sizes, int n_in,
                              void* d_out, int out_size, void* d_ws, size_t ws_size,
                              hipStream_t stream) {
    const float* x = (const float*)d_in[0];   // [8,512,8,512]
    const float* w = (const float*)d_in[1];   // [8,32000,512]
    const float* b = (const float*)d_in[2];   // [8,32000]
    float* out = (float*)d_out;               // [8,512,32000]

    const size_t xbf_bytes = (size_t)M_DIM * K_DIM * 2;
    const size_t wbf_bytes = (size_t)N_DIM * K_DIM * 2;
    const size_t bs_bytes  = (size_t)N_DIM * 4;
    const size_t need = xbf_bytes + wbf_bytes + bs_bytes;

    if (ws_size < need) {
        long total = (long)M_DIM * N_DIM;
        int blocks = (int)((total + 255) / 256);
        naive_out<<<blocks, 256, 0, stream>>>(x, w, b, out);
        return;
    }

    unsigned short* xbf = (unsigned short*)d_ws;
    unsigned short* wbf = (unsigned short*)((char*)d_ws + xbf_bytes);
    float* bsum = (float*)((char*)d_ws + xbf_bytes + wbf_bytes);

    cvt_x<<<8192, 256, 0, stream>>>(x, xbf);
    cvt_w<<<64000, 256, 0, stream>>>(w, wbf);
    bias_red<<<125, 256, 0, stream>>>(b, bsum);
    gemm128<<<8000, 256, 0, stream>>>(xbf, wbf, bsum, out);  // 32 x 250 tiles
}

// Round 8
// 1145.217 us; speedup vs baseline: 1.4095x; 1.4095x over previous
//
#include <hip/hip_runtime.h>
#include <hip/hip_bf16.h>
#include <stdint.h>

// Problem constants
#define NHEAD 8
#define DMODEL 512
#define DVOCAB 32000
#define M_DIM 4096            // B*P
#define K_DIM 4096            // NHEAD*DMODEL
#define N_DIM 32000           // DVOCAB
#define NT    64              // K_DIM / 64 k-tiles

typedef short bf16x8 __attribute__((ext_vector_type(8)));
typedef float f32x16 __attribute__((ext_vector_type(16)));
typedef unsigned short ushort8 __attribute__((ext_vector_type(8)));

template <int V> struct IC { static constexpr int v = V; };

__device__ __forceinline__ unsigned short f2bf(float f) {
    unsigned int u = __builtin_bit_cast(unsigned int, f);
    u = (u + 0x7fffu + ((u >> 16) & 1u)) >> 16;   // RNE (inputs are finite)
    return (unsigned short)u;
}

__device__ __forceinline__ void load16_to_lds(const void* g, void* l) {
    __builtin_amdgcn_global_load_lds(
        (const __attribute__((address_space(1))) unsigned int*)g,
        (__attribute__((address_space(3))) unsigned int*)l, 16, 0, 0);
}

// ---- x [4096][4096] f32 -> bf16, 8 elems/thread ----
__global__ void cvt_x(const float* __restrict__ in, unsigned short* __restrict__ out) {
    long t = (long)blockIdx.x * 256 + threadIdx.x;
    const float4* s = (const float4*)in + t * 2;
    float4 a = s[0], b = s[1];
    ushort8 o;
    o[0] = f2bf(a.x); o[1] = f2bf(a.y); o[2] = f2bf(a.z); o[3] = f2bf(a.w);
    o[4] = f2bf(b.x); o[5] = f2bf(b.y); o[6] = f2bf(b.z); o[7] = f2bf(b.w);
    *(ushort8*)(out + t * 8) = o;
}

// ---- W [H][V][D] f32 -> Wb [V][H*D] bf16 (B^T layout), 8 elems/thread ----
__global__ void cvt_w(const float* __restrict__ in, unsigned short* __restrict__ out) {
    int t = blockIdx.x * 256 + threadIdx.x;
    int d8 = t & 63;
    int hv = t >> 6;
    int h = hv / DVOCAB;
    int v = hv - h * DVOCAB;
    const float4* s = (const float4*)(in + (long)hv * DMODEL + d8 * 8);
    float4 a = s[0], b = s[1];
    ushort8 o;
    o[0] = f2bf(a.x); o[1] = f2bf(a.y); o[2] = f2bf(a.z); o[3] = f2bf(a.w);
    o[4] = f2bf(b.x); o[5] = f2bf(b.y); o[6] = f2bf(b.z); o[7] = f2bf(b.w);
    *(ushort8*)(out + (long)v * K_DIM + h * DMODEL + d8 * 8) = o;
}

// ---- bias [H][V] -> bsum [V] ----
__global__ void bias_red(const float* __restrict__ b, float* __restrict__ out) {
    int v = blockIdx.x * 256 + threadIdx.x;
    if (v >= DVOCAB) return;
    float s = 0.f;
    #pragma unroll
    for (int h = 0; h < NHEAD; ++h) s += b[h * DVOCAB + v];
    out[v] = s;
}

#define BAR()    __builtin_amdgcn_s_barrier()
#define LGKM0()  asm volatile("s_waitcnt lgkmcnt(0)" ::: "memory")
#define VMCNT6() asm volatile("s_waitcnt vmcnt(6)" ::: "memory")
#define VMCNT0() asm volatile("s_waitcnt vmcnt(0)" ::: "memory")

// ---- bf16 GEMM, 256x256 tile, BK=64, 8-phase (r3 schedule), 32x32x16 MFMA ----
// C[M,N] = A[M,K] * Bt[N,K]^T + bias
// Per-wave output 128x64 = acc[4 mi][2 nj] of 32x32 frags.
// A/B operand layout: row|col = lane&31, k = (lane>>5)*8 + i (contiguous 8,
//   matches gfx942 32x32x16_bf8 calculator layout + gfx950 16x16x32 analog).
// C/D: col = lane&31, row = (reg&3) + 8*(reg>>2) + 4*(lane>>5)  [m74/m101].
__global__ __launch_bounds__(512, 2) void gemm256(
    const unsigned short* __restrict__ A,   // [4096][4096] bf16
    const unsigned short* __restrict__ B,   // [32000][4096] bf16
    const float* __restrict__ bias,         // [32000]
    float* __restrict__ C)                  // [4096][32000] f32
{
    __shared__ __attribute__((aligned(16))) unsigned short lds[2][2][2][8192];

    const int tid = threadIdx.x;
    const int bid = blockIdx.x;
    // Locality swizzle: XCD owns 2 M-bands; nt swept time-synced across XCDs
    // so each B-panel's 16 consumer blocks run in one window (1 HBM fetch).
    const int xcd = bid & 7, j = bid >> 3;   // j in 0..249
    const int mt = xcd * 2 + (j & 1);        // 16 M-tiles
    const int nt = j >> 1;                   // 125 N-tiles
    const long m0 = (long)mt * 256;
    const long n0 = (long)nt * 256;

    const int wid = tid >> 6, lane = tid & 63;
    const int wr = wid >> 2, wc = wid & 3;   // 2 x 4 waves
    const int l31 = lane & 31, lhi = lane >> 5, r7 = lane & 7;

    // ds_read base pointers, one per k-step: slot = ((ks<<1)|lhi) ^ r7
    // (stage involution cancels: LDS[row][slot] holds global chunk slot^(row&7),
    //  and row&7 == lane&7 for every fragment row)
    // Wave wr's A rows inside a 128-row half-buffer: wr*64 + mi*32 + l31.
    const unsigned short* pA[4];
    const unsigned short* pB[4];
    #pragma unroll
    for (int ks = 0; ks < 4; ++ks) {
        const int slot = ((ks << 1) | lhi) ^ r7;
        pA[ks] = &lds[0][0][0][0] + (wr * 64 + l31) * 64 + slot * 8;   // FIX: wr*64
        pB[ks] = &lds[1][0][0][0] + (wc * 32 + l31) * 64 + slot * 8;
    }
    // immediates: mi*32 rows = 2048 elems; half = 16384; buf = 8192
    #define LDA(mi, ks, HALF, CURB) \
        (*(const bf16x8*)(pA[ks] + (mi) * 2048 + (HALF) * 16384 + (CURB) * 8192))
    #define LDB(ks, HALF, CURB) \
        (*(const bf16x8*)(pB[ks] + (HALF) * 16384 + (CURB) * 8192))

    // staging: per-lane 32-bit byte offsets off uniform bases, advanced +128B/use
    const char* Ab = (const char*)(A + m0 * K_DIM);
    const char* Bb = (const char*)(B + n0 * K_DIM);
    const int row0 = tid >> 3,         c0 = (tid & 7) ^ (row0 & 7);
    const int row1 = (512 + tid) >> 3, c1 = ((512 + tid) & 7) ^ (row1 & 7);
    unsigned int a00 = (unsigned)(row0 * K_DIM + c0 * 8) * 2u;
    unsigned int a01 = (unsigned)(row1 * K_DIM + c1 * 8) * 2u;
    unsigned int a10 = (unsigned)((128 + row0) * K_DIM + c0 * 8) * 2u;
    unsigned int a11 = (unsigned)((128 + row1) * K_DIM + c1 * 8) * 2u;
    unsigned int b00 = a00, b01 = a01, b10 = a10, b11 = a11;

    #define ST_A0(CURB) do { \
        load16_to_lds(Ab + a00, (char*)&lds[0][0][(CURB)][0] + tid * 16); \
        load16_to_lds(Ab + a01, (char*)&lds[0][0][(CURB)][0] + 8192 + tid * 16); \
        a00 += 128; a01 += 128; } while (0)
    #define ST_A1(CURB) do { \
        load16_to_lds(Ab + a10, (char*)&lds[0][1][(CURB)][0] + tid * 16); \
        load16_to_lds(Ab + a11, (char*)&lds[0][1][(CURB)][0] + 8192 + tid * 16); \
        a10 += 128; a11 += 128; } while (0)
    #define ST_B0(CURB) do { \
        load16_to_lds(Bb + b00, (char*)&lds[1][0][(CURB)][0] + tid * 16); \
        load16_to_lds(Bb + b01, (char*)&lds[1][0][(CURB)][0] + 8192 + tid * 16); \
        b00 += 128; b01 += 128; } while (0)
    #define ST_B1(CURB) do { \
        load16_to_lds(Bb + b10, (char*)&lds[1][1][(CURB)][0] + tid * 16); \
        load16_to_lds(Bb + b11, (char*)&lds[1][1][(CURB)][0] + 8192 + tid * 16); \
        b10 += 128; b11 += 128; } while (0)

    // one phase = one C-quadrant x K=64: 8 MFMAs of 32x32x16
    #define MFPH(AF, BF, MO, NO) do {                                          \
        _Pragma("unroll")                                                      \
        for (int ks = 0; ks < 4; ++ks)                                         \
            _Pragma("unroll")                                                  \
            for (int mi = 0; mi < 2; ++mi)                                     \
                acc[(MO) + mi][NO] = __builtin_amdgcn_mfma_f32_32x32x16_bf16(  \
                    AF[mi][ks], BF[ks], acc[(MO) + mi][NO], 0, 0, 0);          \
    } while (0)

    f32x16 acc[4][2];
    #pragma unroll
    for (int i = 0; i < 4; ++i)
        #pragma unroll
        for (int jn = 0; jn < 2; ++jn)
            #pragma unroll
            for (int r = 0; r < 16; ++r)
                acc[i][jn][r] = 0.f;

    bf16x8 afL[2][4], afH[2][4], bf0[4], bf1[4];

    // prologue: stage tile0 fully + tile1 {A0,B0,B1}; keep 6 in flight
    ST_A0(0); ST_B0(0); ST_B1(0); ST_A1(0);
    ST_A0(1); ST_B0(1); ST_B1(1);
    VMCNT6();
    BAR();

    auto body = [&](auto curc, int t) {
        constexpr int CUR = decltype(curc)::v;

        // ---- P1: read afL(8) + bf0(4); stage (t+1).A1; quad(L,0)
        #pragma unroll
        for (int mi = 0; mi < 2; ++mi)
            #pragma unroll
            for (int ks = 0; ks < 4; ++ks)
                afL[mi][ks] = LDA(mi, ks, 0, CUR);
        #pragma unroll
        for (int ks = 0; ks < 4; ++ks)
            bf0[ks] = LDB(ks, 0, CUR);
        if (t + 1 < NT) ST_A1(CUR ^ 1);
        BAR(); LGKM0();
        __builtin_amdgcn_s_setprio(1);
        MFPH(afL, bf0, 0, 0);
        __builtin_amdgcn_s_setprio(0);
        BAR();

        // ---- P2: read bf1(4); stage (t+2).A0; quad(L,1)
        #pragma unroll
        for (int ks = 0; ks < 4; ++ks)
            bf1[ks] = LDB(ks, 1, CUR);
        if (t + 2 < NT) ST_A0(CUR);
        BAR(); LGKM0();
        __builtin_amdgcn_s_setprio(1);
        MFPH(afL, bf1, 0, 1);
        __builtin_amdgcn_s_setprio(0);
        BAR();

        // ---- P3: read afH(8); stage (t+2).B0; quad(H,0)
        #pragma unroll
        for (int mi = 0; mi < 2; ++mi)
            #pragma unroll
            for (int ks = 0; ks < 4; ++ks)
                afH[mi][ks] = LDA(mi, ks, 1, CUR);
        if (t + 2 < NT) ST_B0(CUR);
        BAR(); LGKM0();
        __builtin_amdgcn_s_setprio(1);
        MFPH(afH, bf0, 2, 0);
        __builtin_amdgcn_s_setprio(0);
        BAR();

        // ---- P4: stage (t+2).B1; counted vmcnt; quad(H,1)
        if (t + 2 < NT) ST_B1(CUR);
        if (t < NT - 2) { VMCNT6(); } else { VMCNT0(); }
        BAR();
        __builtin_amdgcn_s_setprio(1);
        MFPH(afH, bf1, 2, 1);
        __builtin_amdgcn_s_setprio(0);
        BAR();
    };

    for (int t = 0; t < NT; t += 2) {
        body(IC<0>{}, t);
        body(IC<1>{}, t + 1);
    }
    #undef LDA
    #undef LDB
    #undef ST_A0
    #undef ST_A1
    #undef ST_B0
    #undef ST_B1
    #undef MFPH

    // epilogue: col = lane&31 (128B segments/reg), row = (reg&3)+8*(reg>>2)+4*lhi
    #pragma unroll
    for (int nj = 0; nj < 2; ++nj) {
        const long col = n0 + nj * 128 + wc * 32 + l31;
        const float bs = bias[col];
        #pragma unroll
        for (int mi = 0; mi < 4; ++mi) {
            const long rowb = m0 + (mi >> 1) * 128 + wr * 64 + (mi & 1) * 32 + lhi * 4;
            #pragma unroll
            for (int r = 0; r < 16; ++r) {
                const long row = rowb + (r & 3) + 8 * (r >> 2);
                __builtin_nontemporal_store(acc[mi][nj][r] + bs,
                                            &C[row * (long)N_DIM + col]);
            }
        }
    }
}

// ---- emergency fallback if ws too small: naive fp32 (slow but correct) ----
__global__ void naive_out(const float* __restrict__ x, const float* __restrict__ w,
                          const float* __restrict__ b, float* __restrict__ out) {
    long idx = (long)blockIdx.x * 256 + threadIdx.x;
    if (idx >= (long)M_DIM * N_DIM) return;
    long m = idx / N_DIM;
    int v = (int)(idx - m * N_DIM);
    float s = 0.f;
    for (int h = 0; h < NHEAD; ++h) {
        const float* xr = x + m * K_DIM + h * DMODEL;
        const float* wr = w + ((long)h * DVOCAB + v) * DMODEL;
        float ps = 0.f;
        for (int d = 0; d < DMODEL; ++d) ps += xr[d] * wr[d];
        s += ps + b[h * DVOCAB + v];
    }
    out[idx] = s;
}

extern "C" void kernel_launch(void* const* d_in, const int* in_sizes, int n_in,
                              void* d_out, int out_size, void* d_ws, size_t ws_size,
                              hipStream_t stream) {
    const float* x = (const float*)d_in[0];   // [8,512,8,512]
    const float* w = (const float*)d_in[1];   // [8,32000,512]
    const float* b = (const float*)d_in[2];   // [8,32000]
    float* out = (float*)d_out;               // [8,512,32000]

    const size_t xbf_bytes = (size_t)M_DIM * K_DIM * 2;
    const size_t wbf_bytes = (size_t)N_DIM * K_DIM * 2;
    const size_t bs_bytes  = (size_t)N_DIM * 4;
    const size_t need = xbf_bytes + wbf_bytes + bs_bytes;

    if (ws_size < need) {
        long total = (long)M_DIM * N_DIM;
        int blocks = (int)((total + 255) / 256);
        naive_out<<<blocks, 256, 0, stream>>>(x, w, b, out);
        return;
    }

    unsigned short* xbf = (unsigned short*)d_ws;
    unsigned short* wbf = (unsigned short*)((char*)d_ws + xbf_bytes);
    float* bsum = (float*)((char*)d_ws + xbf_bytes + wbf_bytes);

    cvt_x<<<8192, 256, 0, stream>>>(x, xbf);
    cvt_w<<<64000, 256, 0, stream>>>(w, wbf);
    bias_red<<<125, 256, 0, stream>>>(b, bsum);
    gemm256<<<2000, 512, 0, stream>>>(xbf, wbf, bsum, out);  // 16 x 125 tiles
}